// Round 1
// baseline (237.538 us; speedup 1.0000x reference)
//
#include <hip/hip_runtime.h>

// Sparsemax over rows: out = relu(x - tau), tau s.t. sum(relu(x - tau)) = 1.
// Newton/Michelot iteration: tau <- (S - 1)/K over support {x > tau}.
// Converges finitely (piecewise-linear convex f); ~4-8 iters on Gaussian rows.

constexpr int D       = 8192;       // row length
constexpr int THREADS = 256;        // one block per row
constexpr int F4PT    = D / (THREADS * 4);   // 8 float4 per thread (32 floats)

// Block-wide sum of two values. 4 waves of 64 lanes.
__device__ __forceinline__ void block_reduce2(float& a, float& b, float* lds) {
    #pragma unroll
    for (int off = 1; off < 64; off <<= 1) {
        a += __shfl_xor(a, off, 64);
        b += __shfl_xor(b, off, 64);
    }
    const int wave = threadIdx.x >> 6;
    const int lane = threadIdx.x & 63;
    __syncthreads();                       // protect lds reuse across calls
    if (lane == 0) { lds[wave] = a; lds[4 + wave] = b; }
    __syncthreads();
    a = (lds[0] + lds[1]) + (lds[2] + lds[3]);
    b = (lds[4] + lds[5]) + (lds[6] + lds[7]);
}

__global__ __launch_bounds__(THREADS, 4)
void sparsemax_kernel(const float* __restrict__ x, float* __restrict__ out) {
    __shared__ float lds[8];
    const long long row = blockIdx.x;
    const float* __restrict__ xr  = x   + row * (long long)D;
    float* __restrict__       orw = out + row * (long long)D;
    const int tid = threadIdx.x;

    // Stage entire row in registers: coalesced float4 loads (1 KiB/wave/inst).
    float4 v[F4PT];
    #pragma unroll
    for (int i = 0; i < F4PT; ++i)
        v[i] = reinterpret_cast<const float4*>(xr)[tid + i * THREADS];

    // tau0 = (sum - 1)/d  -> f(tau0) >= 0, Newton proceeds monotonically up.
    float s = 0.f, z = 0.f;
    #pragma unroll
    for (int i = 0; i < F4PT; ++i)
        s += (v[i].x + v[i].y) + (v[i].z + v[i].w);
    block_reduce2(s, z, lds);

    float tau   = (s - 1.f) / (float)D;
    float kprev = (float)D;

    // Newton (Michelot) iterations; trip count data-dependent but branch is
    // block-uniform (K comes from the block reduction). Cap for safety.
    for (int it = 0; it < 64; ++it) {
        float S = 0.f, K = 0.f;
        #pragma unroll
        for (int i = 0; i < F4PT; ++i) {
            float e;
            e = v[i].x; if (e > tau) { S += e; K += 1.f; }
            e = v[i].y; if (e > tau) { S += e; K += 1.f; }
            e = v[i].z; if (e > tau) { S += e; K += 1.f; }
            e = v[i].w; if (e > tau) { S += e; K += 1.f; }
        }
        block_reduce2(S, K, lds);
        if (K < 0.5f) break;               // fp-safety guard (shouldn't happen)
        tau = (S - 1.f) / K;
        if (K == kprev) break;             // support unchanged -> fixed point
        kprev = K;
    }

    // out = relu(x - tau), coalesced float4 stores.
    #pragma unroll
    for (int i = 0; i < F4PT; ++i) {
        float4 o;
        o.x = fmaxf(v[i].x - tau, 0.f);
        o.y = fmaxf(v[i].y - tau, 0.f);
        o.z = fmaxf(v[i].z - tau, 0.f);
        o.w = fmaxf(v[i].w - tau, 0.f);
        reinterpret_cast<float4*>(orw)[tid + i * THREADS] = o;
    }
}

extern "C" void kernel_launch(void* const* d_in, const int* in_sizes, int n_in,
                              void* d_out, int out_size, void* d_ws, size_t ws_size,
                              hipStream_t stream) {
    const float* x = (const float*)d_in[0];
    float* out = (float*)d_out;
    const int rows = in_sizes[0] / D;      // 4096
    sparsemax_kernel<<<rows, THREADS, 0, stream>>>(x, out);
}

// Round 3
// 235.431 us; speedup vs baseline: 1.0090x; 1.0090x over previous
//
#include <hip/hip_runtime.h>
#include <float.h>

// Sparsemax per row: out = relu(x - tau), tau s.t. sum(relu(x - tau)) = 1.
// Key bound: tau >= max(x) - 1, so only elements > max-1 can be in the
// support (~20 of 8192 for Gaussian rows). Gather those into a tiny list,
// run Michelot/Newton on registers; row staged in LDS so HBM sees 1R + 1W.

constexpr int D       = 8192;
constexpr int THREADS = 256;                  // one block per row
constexpr int F4PT    = D / (THREADS * 4);    // 8 float4 per thread
constexpr int VPT     = D / THREADS;          // 32 floats per thread
constexpr int CAP     = 1024;                 // candidate-list capacity

typedef float f32x4 __attribute__((ext_vector_type(4)));  // native vec for builtins

// Block-wide sum of two values (4 waves of 64).
__device__ __forceinline__ void block_reduce2(float& a, float& b, float* red) {
    #pragma unroll
    for (int off = 1; off < 64; off <<= 1) {
        a += __shfl_xor(a, off, 64);
        b += __shfl_xor(b, off, 64);
    }
    const int wave = threadIdx.x >> 6;
    const int lane = threadIdx.x & 63;
    __syncthreads();                 // protect red reuse across calls
    if (lane == 0) { red[wave] = a; red[4 + wave] = b; }
    __syncthreads();
    a = (red[0] + red[1]) + (red[2] + red[3]);
    b = (red[4] + red[5]) + (red[6] + red[7]);
}

__global__ __launch_bounds__(THREADS, 4)
void sparsemax_kernel(const float* __restrict__ x, float* __restrict__ out) {
    __shared__ float row[D];        // 32 KiB staged row
    __shared__ float cands[CAP];    // 4 KiB candidate list
    __shared__ float red[8];
    __shared__ int   cnt;

    const long long r = blockIdx.x;
    const f32x4* __restrict__ xr4 = reinterpret_cast<const f32x4*>(x + r * (long long)D);
    f32x4* __restrict__       or4 = reinterpret_cast<f32x4*>(out + r * (long long)D);
    f32x4* row4 = reinterpret_cast<f32x4*>(row);
    const int tid  = threadIdx.x;
    const int wave = tid >> 6, lane = tid & 63;

    if (tid == 0) cnt = 0;

    // Pass 1: global -> LDS, computing the row max on the fly.
    float m = -FLT_MAX;
    #pragma unroll
    for (int i = 0; i < F4PT; ++i) {
        f32x4 t = xr4[tid + i * THREADS];
        row4[tid + i * THREADS] = t;
        m = fmaxf(m, fmaxf(fmaxf(t.x, t.y), fmaxf(t.z, t.w)));
    }
    #pragma unroll
    for (int off = 1; off < 64; off <<= 1)
        m = fmaxf(m, __shfl_xor(m, off, 64));
    __syncthreads();                 // row + cnt=0 visible
    if (lane == 0) red[wave] = m;
    __syncthreads();
    m = fmaxf(fmaxf(red[0], red[1]), fmaxf(red[2], red[3]));
    const float thr = m - 1.0f;      // tau >= thr always

    // Pass 2: gather candidates (x > thr). ~20 atomics per block.
    #pragma unroll
    for (int j = 0; j < VPT; ++j) {
        float v = row[tid + j * THREADS];
        if (v > thr) {
            int p = atomicAdd(&cnt, 1);
            if (p < CAP) cands[p] = v;
        }
    }
    __syncthreads();
    const int n = cnt;

    float tau;
    if (n <= CAP) {
        // Candidates to registers (static indexing; -FLT_MAX sentinel never > tau).
        float c0 = (tid               < n) ? cands[tid              ] : -FLT_MAX;
        float c1 = (tid +     THREADS < n) ? cands[tid +     THREADS] : -FLT_MAX;
        float c2 = (tid + 2 * THREADS < n) ? cands[tid + 2 * THREADS] : -FLT_MAX;
        float c3 = (tid + 3 * THREADS < n) ? cands[tid + 3 * THREADS] : -FLT_MAX;
        // Michelot from tau0 = max-1: f(tau0) >= 0, tau increases monotonically,
        // support only shrinks; finite convergence (support-size fixed point).
        tau = thr;
        float kprev = -1.0f;
        for (int it = 0; it < 32; ++it) {      // block-uniform trip count
            float S = 0.f, K = 0.f;
            if (c0 > tau) { S += c0; K += 1.f; }
            if (c1 > tau) { S += c1; K += 1.f; }
            if (c2 > tau) { S += c2; K += 1.f; }
            if (c3 > tau) { S += c3; K += 1.f; }
            block_reduce2(S, K, red);
            tau = (S - 1.f) / K;               // K >= 1: max always in support
            if (K == kprev) break;
            kprev = K;
        }
    } else {
        // Fallback (unreachable for Gaussian input): full-row Michelot over LDS.
        float s = 0.f, z = 0.f;
        #pragma unroll
        for (int j = 0; j < VPT; ++j) s += row[tid + j * THREADS];
        block_reduce2(s, z, red);
        tau = (s - 1.f) / (float)D;
        float kprev = (float)D;
        for (int it = 0; it < 64; ++it) {
            float S = 0.f, K = 0.f;
            #pragma unroll
            for (int j = 0; j < VPT; ++j) {
                float v = row[tid + j * THREADS];
                if (v > tau) { S += v; K += 1.f; }
            }
            block_reduce2(S, K, red);
            if (K < 0.5f) break;
            tau = (S - 1.f) / K;
            if (K == kprev) break;
            kprev = K;
        }
    }

    // Pass 3: LDS -> relu(x - tau) -> global, nontemporal float4 stores.
    #pragma unroll
    for (int i = 0; i < F4PT; ++i) {
        f32x4 t = row4[tid + i * THREADS];
        f32x4 o;
        o.x = fmaxf(t.x - tau, 0.f);
        o.y = fmaxf(t.y - tau, 0.f);
        o.z = fmaxf(t.z - tau, 0.f);
        o.w = fmaxf(t.w - tau, 0.f);
        __builtin_nontemporal_store(o, &or4[tid + i * THREADS]);
    }
}

extern "C" void kernel_launch(void* const* d_in, const int* in_sizes, int n_in,
                              void* d_out, int out_size, void* d_ws, size_t ws_size,
                              hipStream_t stream) {
    const float* x = (const float*)d_in[0];
    float* out = (float*)d_out;
    const int rows = in_sizes[0] / D;      // 4096
    sparsemax_kernel<<<rows, THREADS, 0, stream>>>(x, out);
}